// Round 20
// baseline (281.474 us; speedup 1.0000x reference)
//
#include <hip/hip_runtime.h>
#include <hip/hip_bf16.h>
#include <math.h>

#define B_TOK 8192
#define DDIM 1024
#define NEXP 8
#define HDIM 2048
#define CDIM 512
#define LN_EPS 1e-5f
#define MAXT256 72
#define MAXROWS (MAXT256 * 256)

typedef __attribute__((ext_vector_type(4))) float f32x4;
typedef __attribute__((ext_vector_type(8))) short bf16x8;

__device__ __forceinline__ unsigned short f2bf(float f) {
  __hip_bfloat16 h = __float2bfloat16(f);
  return *reinterpret_cast<unsigned short*>(&h);
}
__device__ __forceinline__ float bf2f(unsigned short u) {
  unsigned int x = ((unsigned int)u) << 16;
  return *reinterpret_cast<float*>(&x);
}

// gelu tanh-form via sigmoid identity: ~9 VALU ops, max dev vs exact ~3e-4
__device__ __forceinline__ float gelu_f(float v) {
  const float t = __builtin_fmaf(0.044715f * v, v, 1.0f);
  const float u = -1.5957691216f * v * t;
  return v * __builtin_amdgcn_rcpf(1.0f + __expf(u));
}

__device__ __forceinline__ void gload_lds16(const unsigned short* g, unsigned short* l) {
  __builtin_amdgcn_global_load_lds(
      (const __attribute__((address_space(1))) unsigned int*)g,
      (__attribute__((address_space(3))) unsigned int*)l, 16, 0, 0);
}

// ---------------- Router + LayerNorm (1 wave per token) ----------------
__global__ __launch_bounds__(256) void router_ln_kernel(
    const float* __restrict__ x, const float* __restrict__ Wr,
    const float* __restrict__ br, int* __restrict__ eidx,
    float* __restrict__ wgt, unsigned short* __restrict__ xn) {
  const int wid = threadIdx.x >> 6;
  const int lane = threadIdx.x & 63;
  const int tok = blockIdx.x * 4 + wid;

  const float4* xr = reinterpret_cast<const float4*>(x + (size_t)tok * DDIM);
  float4 xv[4];
  float sum = 0.f, sumsq = 0.f;
  float dot[NEXP];
#pragma unroll
  for (int e = 0; e < NEXP; ++e) dot[e] = 0.f;

#pragma unroll
  for (int i = 0; i < 4; ++i) {
    const int f = i * 64 + lane;
    float4 v = xr[f];
    xv[i] = v;
    sum += v.x + v.y + v.z + v.w;
    sumsq += v.x * v.x + v.y * v.y + v.z * v.z + v.w * v.w;
#pragma unroll
    for (int e = 0; e < NEXP; ++e) {
      float4 w = reinterpret_cast<const float4*>(Wr + e * DDIM)[f];
      dot[e] += v.x * w.x + v.y * w.y + v.z * w.z + v.w * w.w;
    }
  }
#pragma unroll
  for (int off = 32; off > 0; off >>= 1) {
    sum += __shfl_xor(sum, off);
    sumsq += __shfl_xor(sumsq, off);
#pragma unroll
    for (int e = 0; e < NEXP; ++e) dot[e] += __shfl_xor(dot[e], off);
  }
  const float mu = sum * (1.f / DDIM);
  const float var = sumsq * (1.f / DDIM) - mu * mu;
  const float rs = rsqrtf(var + LN_EPS);

  float lg[NEXP];
#pragma unroll
  for (int e = 0; e < NEXP; ++e) lg[e] = dot[e] + br[e];

  int i1 = 0; float v1 = lg[0];
#pragma unroll
  for (int e = 1; e < NEXP; ++e) { if (lg[e] > v1) { v1 = lg[e]; i1 = e; } }
  int i2 = -1; float v2 = -3.4e38f;
#pragma unroll
  for (int e = 0; e < NEXP; ++e) { if (e != i1 && lg[e] > v2) { v2 = lg[e]; i2 = e; } }

  const float e2 = __expf(v2 - v1);
  const float inv = 1.f / (1.f + e2);
  if (lane == 0) {
    eidx[tok * 2] = i1; eidx[tok * 2 + 1] = i2;
    wgt[tok * 2] = inv; wgt[tok * 2 + 1] = e2 * inv;
  }

  unsigned short* xnr = xn + (size_t)tok * DDIM;
#pragma unroll
  for (int i = 0; i < 4; ++i) {
    const int f = i * 64 + lane;
    float4 v = xv[i];
    ushort4 o;
    o.x = f2bf((v.x - mu) * rs);
    o.y = f2bf((v.y - mu) * rs);
    o.z = f2bf((v.z - mu) * rs);
    o.w = f2bf((v.w - mu) * rs);
    reinterpret_cast<ushort4*>(xnr)[f] = o;
  }
}

// ---------------- Counting sort into 256-row expert tiles ----------------
__global__ __launch_bounds__(256) void sort_kernel(
    const int* __restrict__ eidx,   // [B*2]
    int* __restrict__ tokRow,       // [MAXROWS]
    int* __restrict__ slot2row,     // [B*2]
    int* __restrict__ tileExp,      // [MAXT256]
    int* __restrict__ nTilesOut) {
  __shared__ int cnt[NEXP], segBase[NEXP], cur[NEXP];
  const int tid = threadIdx.x;
  if (tid < NEXP) { cnt[tid] = 0; cur[tid] = 0; }
  __syncthreads();
  for (int t = tid; t < B_TOK * 2; t += 256)
    atomicAdd(&cnt[eidx[t]], 1);
  __syncthreads();
  if (tid == 0) {
    int c = 0;
    for (int e = 0; e < NEXP; ++e) {
      segBase[e] = c;
      const int nt = (cnt[e] + 255) >> 8;
      for (int t = 0; t < nt; ++t) tileExp[(c >> 8) + t] = e;
      for (int p = c + cnt[e]; p < c + nt * 256; ++p) tokRow[p] = 0;
      c += nt * 256;
    }
    *nTilesOut = c >> 8;
  }
  __syncthreads();
  for (int t = tid; t < B_TOK * 2; t += 256) {
    const int e = eidx[t];
    const int pos = segBase[e] + atomicAdd(&cur[e], 1);
    tokRow[pos] = t >> 1;
    slot2row[t] = pos;
  }
}

// ---------------- Fold gamma/beta into W1: W1g bf16, c1 = beta@W1.T + b1 ----------------
__global__ __launch_bounds__(256) void prep_w1_kernel(
    const float* __restrict__ W1, const float* __restrict__ gamma,
    const float* __restrict__ beta, const float* __restrict__ b1,
    unsigned short* __restrict__ W1g, float* __restrict__ c1) {
  const int eh = blockIdx.x;
  const int e = eh >> 11;
  const int tid = threadIdx.x;

  float4 w = reinterpret_cast<const float4*>(W1 + (size_t)eh * DDIM)[tid];
  float4 g = reinterpret_cast<const float4*>(gamma + (size_t)e * DDIM)[tid];
  float4 bt = reinterpret_cast<const float4*>(beta + (size_t)e * DDIM)[tid];

  ushort4 o;
  o.x = f2bf(w.x * g.x); o.y = f2bf(w.y * g.y);
  o.z = f2bf(w.z * g.z); o.w = f2bf(w.w * g.w);
  reinterpret_cast<ushort4*>(W1g + (size_t)eh * DDIM)[tid] = o;

  float p = w.x * bt.x + w.y * bt.y + w.z * bt.z + w.w * bt.w;
#pragma unroll
  for (int off = 32; off > 0; off >>= 1) p += __shfl_xor(p, off);
  __shared__ float red[4];
  const int lane = tid & 63, wv = tid >> 6;
  if (lane == 0) red[wv] = p;
  __syncthreads();
  if (tid == 0) c1[eh] = b1[eh] + red[0] + red[1] + red[2] + red[3];
}

// ---------------- W2 f32 -> bf16 ----------------
__global__ __launch_bounds__(256) void prep_w2_kernel(
    const float* __restrict__ W2, unsigned short* __restrict__ W2b) {
  const int idx = blockIdx.x * 256 + threadIdx.x;
  float4 w = reinterpret_cast<const float4*>(W2)[idx];
  ushort4 o;
  o.x = f2bf(w.x); o.y = f2bf(w.y); o.z = f2bf(w.z); o.w = f2bf(w.w);
  reinterpret_cast<ushort4*>(W2b)[idx] = o;
}

// ---------------- GEMM1: 128x128, 2-deep dbuf LDS + counted vmcnt ----------------
#define BM 128
#define BN 128
#define BKK 64

__global__ __launch_bounds__(256) void gemm1_gelu_kernel(
    const unsigned short* __restrict__ A,    // xn [B,D] bf16
    const unsigned short* __restrict__ W1g,  // [E,H,D] bf16
    const float* __restrict__ c1,            // [E,H]
    const int* __restrict__ tokRow, const int* __restrict__ tileExp,
    const int* __restrict__ nTiles,
    unsigned short* __restrict__ Hout) {     // [MAXROWS,H] bf16
  // 2304 blocks: by=flat&15 (XCD = by%8 -> W-panels L2-pinned), bx window shared (A via L3)
  const int flat = blockIdx.x;
  const int by = flat & 15;
  const int bx = flat >> 4;            // [0,144)
  if ((bx >> 1) >= *nTiles) return;
  const int e = tileExp[bx >> 1];

  __shared__ unsigned short lA[2][BM * BKK];   // 32 KiB x2
  __shared__ unsigned short lB[2][BN * BKK];   // 32 KiB x2  (total 64 KiB -> 2 blocks/CU)
  const int tid = threadIdx.x;
  const int lane = tid & 63;
  const int wid = tid >> 6;
  const int wr = wid >> 1, wc = wid & 1;
  const int l15 = lane & 15, l4 = lane >> 4;

  const unsigned short* Bbase = W1g + ((size_t)e * HDIM + (size_t)by * BN) * DDIM;

  const int r = tid >> 3;                              // 0..31
  const int swz = ((tid & 7) ^ (r & 7)) * 8;           // inverse-swizzled source offset
  const int dst = (tid & 7) * 8;                       // lane-linear LDS slot

  // hoisted global pointers (k advances via scalar offset)
  const unsigned short* aP[4];
  const unsigned short* bP[4];
#pragma unroll
  for (int i = 0; i < 4; ++i) {
    aP[i] = A + (size_t)tokRow[bx * BM + i * 32 + r] * DDIM + swz;
    bP[i] = Bbase + (size_t)(i * 32 + r) * DDIM + swz;
  }

  f32x4 acc[4][4];   // [nn][mm]
#pragma unroll
  for (int n = 0; n < 4; ++n)
#pragma unroll
    for (int m = 0; m < 4; ++m)
#pragma unroll
      for (int j = 0; j < 4; ++j) acc[n][m][j] = 0.f;

  auto stage = [&](int b, int k0) {
#pragma unroll
    for (int i = 0; i < 4; ++i)
      gload_lds16(aP[i] + k0, &lA[b][(i * 32 + r) * BKK + dst]);
#pragma unroll
    for (int i = 0; i < 4; ++i)
      gload_lds16(bP[i] + k0, &lB[b][(i * 32 + r) * BKK + dst]);
  };

  // prologue: 2 tiles in flight (16 loads/thread outstanding)
  stage(0, 0);
  stage(1, BKK);

#pragma unroll 1
  for (int it = 0; it < 16; ++it) {
    if (it < 15) asm volatile("s_waitcnt vmcnt(8)" ::: "memory");
    else         asm volatile("s_waitcnt vmcnt(0)" ::: "memory");
    __builtin_amdgcn_sched_barrier(0);
    asm volatile("s_barrier" ::: "memory");
    const unsigned short* la = lA[it & 1];
    const unsigned short* lb = lB[it & 1];
#pragma unroll
    for (int kk = 0; kk < 2; ++kk) {
      bf16x8 xf[4], wf[4];
      const int slot = (((kk * 4 + l4) ^ (l15 & 7)) * 8);
#pragma unroll
      for (int m = 0; m < 4; ++m)
        xf[m] = *reinterpret_cast<const bf16x8*>(
            &la[(wr * 64 + m * 16 + l15) * BKK + slot]);
#pragma unroll
      for (int n = 0; n < 4; ++n)
        wf[n] = *reinterpret_cast<const bf16x8*>(
            &lb[(wc * 64 + n * 16 + l15) * BKK + slot]);
      // swapped operands: D(ar=W n-idx, br=token)
#pragma unroll
      for (int n = 0; n < 4; ++n)
#pragma unroll
        for (int m = 0; m < 4; ++m)
          acc[n][m] = __builtin_amdgcn_mfma_f32_16x16x32_bf16(wf[n], xf[m], acc[n][m], 0, 0, 0);
    }
    asm volatile("s_barrier" ::: "memory");
    if (it < 14) stage(it & 1, (it + 2) * BKK);
  }

  const int row0 = bx * BM + wr * 64;   // token base
  const int col0 = by * BN + wc * 64;   // h base
  const float* biasp = c1 + e * HDIM;
#pragma unroll
  for (int n = 0; n < 4; ++n) {
    const int hb = col0 + n * 16 + l4 * 4;
    const float4 b4 = *reinterpret_cast<const float4*>(biasp + hb);
#pragma unroll
    for (int m = 0; m < 4; ++m) {
      const int tokr = row0 + m * 16 + l15;
      ushort4 o;
      o.x = f2bf(gelu_f(acc[n][m][0] + b4.x));
      o.y = f2bf(gelu_f(acc[n][m][1] + b4.y));
      o.z = f2bf(gelu_f(acc[n][m][2] + b4.z));
      o.w = f2bf(gelu_f(acc[n][m][3] + b4.w));
      *reinterpret_cast<ushort4*>(&Hout[(size_t)tokr * HDIM + hb]) = o;
    }
  }
}

// ---------------- GEMM2: 128x128, 2-deep dbuf LDS + counted vmcnt ----------------
__global__ __launch_bounds__(256) void gemm2_kernel(
    const unsigned short* __restrict__ Hbuf,  // [MAXROWS,H] bf16
    const unsigned short* __restrict__ W2b,   // [E,C,H] bf16
    const int* __restrict__ tileExp, const int* __restrict__ nTiles,
    unsigned short* __restrict__ Y) {         // [MAXROWS,C] bf16
  // 576 blocks: XCD p=flat&7 owns by=p>>1 and bx-half p&1.
  const int flat = blockIdx.x;
  const int p = flat & 7;
  const int q = flat >> 3;              // [0,72)
  const int by = p >> 1;                // [0,4)
  const int bx = (p & 1) * 72 + q;      // [0,144)
  if ((bx >> 1) >= *nTiles) return;
  const int e = tileExp[bx >> 1];

  __shared__ unsigned short lA[2][BM * BKK];
  __shared__ unsigned short lB[2][BN * BKK];   // 64 KiB total; grid-limited occupancy unaffected
  const int tid = threadIdx.x;
  const int lane = tid & 63;
  const int wid = tid >> 6;
  const int wr = wid >> 1, wc = wid & 1;
  const int l15 = lane & 15, l4 = lane >> 4;

  const unsigned short* Abase = Hbuf + (size_t)bx * BM * HDIM;
  const unsigned short* Bbase = W2b + ((size_t)e * CDIM + (size_t)by * BN) * HDIM;

  f32x4 acc[4][4];   // [nn][mm]
#pragma unroll
  for (int n = 0; n < 4; ++n)
#pragma unroll
    for (int m = 0; m < 4; ++m)
#pragma unroll
      for (int j = 0; j < 4; ++j) acc[n][m][j] = 0.f;

  const int r = tid >> 3;
  const int swz = ((tid & 7) ^ (r & 7)) * 8;
  const int dst = (tid & 7) * 8;

  auto stage = [&](int b, int k0) {
#pragma unroll
    for (int i = 0; i < 4; ++i)
      gload_lds16(Abase + (size_t)(i * 32 + r) * HDIM + k0 + swz,
                  &lA[b][(i * 32 + r) * BKK + dst]);
#pragma unroll
    for (int i = 0; i < 4; ++i)
      gload_lds16(Bbase + (size_t)(i * 32 + r) * HDIM + k0 + swz,
                  &lB[b][(i * 32 + r) * BKK + dst]);
  };

  stage(0, 0);
  stage(1, BKK);

#pragma unroll 1
  for (int it = 0; it < 32; ++it) {
    if (it < 31) asm volatile("s_waitcnt vmcnt(8)" ::: "memory");
    else         asm volatile("s_waitcnt vmcnt(0)" ::: "memory");
    __builtin_amdgcn_sched_barrier(0);
    asm volatile("s_barrier" ::: "memory");
    const unsigned short* la = lA[it & 1];
    const unsigned short* lb = lB[it & 1];
#pragma unroll
    for (int kk = 0; kk < 2; ++kk) {
      bf16x8 xf[4], wf[4];
      const int slot = (((kk * 4 + l4) ^ (l15 & 7)) * 8);
#pragma unroll
      for (int m = 0; m < 4; ++m)
        xf[m] = *reinterpret_cast<const bf16x8*>(
            &la[(wr * 64 + m * 16 + l15) * BKK + slot]);
#pragma unroll
      for (int n = 0; n < 4; ++n)
        wf[n] = *reinterpret_cast<const bf16x8*>(
            &lb[(wc * 64 + n * 16 + l15) * BKK + slot]);
#pragma unroll
      for (int n = 0; n < 4; ++n)
#pragma unroll
        for (int m = 0; m < 4; ++m)
          acc[n][m] = __builtin_amdgcn_mfma_f32_16x16x32_bf16(wf[n], xf[m], acc[n][m], 0, 0, 0);
    }
    asm volatile("s_barrier" ::: "memory");
    if (it < 30) stage(it & 1, (it + 2) * BKK);
  }

  const int row0 = bx * BM + wr * 64;   // token base
  const int col0 = by * BN + wc * 64;   // C base
#pragma unroll
  for (int n = 0; n < 4; ++n) {
    const int cb = col0 + n * 16 + l4 * 4;
#pragma unroll
    for (int m = 0; m < 4; ++m) {
      const int tokr = row0 + m * 16 + l15;
      ushort4 o;
      o.x = f2bf(acc[n][m][0]);
      o.y = f2bf(acc[n][m][1]);
      o.z = f2bf(acc[n][m][2]);
      o.w = f2bf(acc[n][m][3]);
      *reinterpret_cast<ushort4*>(&Y[(size_t)tokr * CDIM + cb]) = o;
    }
  }
}

// ---------------- Combine: out[b,c] = sum_j w_j * (y[r_j,c] + b2[e_j,c]) ----------------
__global__ __launch_bounds__(256) void combine_kernel(
    const unsigned short* __restrict__ Y, const int* __restrict__ slot2row,
    const int* __restrict__ eidx, const float* __restrict__ wgt,
    const float* __restrict__ b2, float* __restrict__ out) {
  const int idx = blockIdx.x * 256 + threadIdx.x;
  const int b = idx >> 7;
  const int c4 = (idx & 127) * 4;
  const int r0 = slot2row[b * 2], r1 = slot2row[b * 2 + 1];
  const int e0 = eidx[b * 2], e1 = eidx[b * 2 + 1];
  const float w0 = wgt[b * 2], w1 = wgt[b * 2 + 1];
  ushort4 y0 = *reinterpret_cast<const ushort4*>(Y + (size_t)r0 * CDIM + c4);
  ushort4 y1 = *reinterpret_cast<const ushort4*>(Y + (size_t)r1 * CDIM + c4);
  float4 bb0 = *reinterpret_cast<const float4*>(b2 + e0 * CDIM + c4);
  float4 bb1 = *reinterpret_cast<const float4*>(b2 + e1 * CDIM + c4);
  float4 o;
  o.x = w0 * (bf2f(y0.x) + bb0.x) + w1 * (bf2f(y1.x) + bb1.x);
  o.y = w0 * (bf2f(y0.y) + bb0.y) + w1 * (bf2f(y1.y) + bb1.y);
  o.z = w0 * (bf2f(y0.z) + bb0.z) + w1 * (bf2f(y1.z) + bb1.z);
  o.w = w0 * (bf2f(y0.w) + bb0.w) + w1 * (bf2f(y1.w) + bb1.w);
  *reinterpret_cast<float4*>(out + (size_t)b * CDIM + c4) = o;
}

extern "C" void kernel_launch(void* const* d_in, const int* in_sizes, int n_in,
                              void* d_out, int out_size, void* d_ws, size_t ws_size,
                              hipStream_t stream) {
  const float* x     = (const float*)d_in[0];
  const float* Wr    = (const float*)d_in[1];
  const float* br    = (const float*)d_in[2];
  const float* gamma = (const float*)d_in[3];
  const float* beta  = (const float*)d_in[4];
  const float* W1    = (const float*)d_in[5];
  const float* b1    = (const float*)d_in[6];
  const float* W2    = (const float*)d_in[7];
  const float* b2    = (const float*)d_in[8];
  float* out = (float*)d_out;

  char* ws = (char*)d_ws;
  unsigned short* xn   = (unsigned short*)(ws);
  unsigned short* W2b  = (unsigned short*)(ws);                          // alias of xn (dead after gemm1)
  unsigned short* hbuf = (unsigned short*)(ws + (size_t)16 * 1048576);
  unsigned short* W1g  = (unsigned short*)(ws + (size_t)88 * 1048576);
  unsigned short* ybuf = (unsigned short*)(ws + (size_t)88 * 1048576);   // alias of W1g
  char* misc           = ws + (size_t)120 * 1048576;
  float* c1      = (float*)(misc);
  int* eidx      = (int*)(misc + 65536);
  float* wgt     = (float*)(misc + 2 * 65536);
  int* slot2row  = (int*)(misc + 3 * 65536);
  int* tokRow    = (int*)(misc + 4 * 65536);
  int* tileExp   = (int*)(misc + 4 * 65536 + 131072);
  int* nTiles    = tileExp + MAXT256;

  router_ln_kernel<<<dim3(B_TOK / 4), dim3(256), 0, stream>>>(x, Wr, br, eidx, wgt, xn);
  sort_kernel<<<dim3(1), dim3(256), 0, stream>>>(eidx, tokRow, slot2row, tileExp, nTiles);
  prep_w1_kernel<<<dim3(NEXP * HDIM), dim3(256), 0, stream>>>(W1, gamma, beta, b1, W1g, c1);

  gemm1_gelu_kernel<<<dim3(2304), dim3(256), 0, stream>>>(
      xn, W1g, c1, tokRow, tileExp, nTiles, hbuf);

  prep_w2_kernel<<<dim3((NEXP * CDIM * HDIM / 4) / 256), dim3(256), 0, stream>>>(W2, W2b);

  gemm2_kernel<<<dim3(576), dim3(256), 0, stream>>>(
      hbuf, W2b, tileExp, nTiles, ybuf);
  combine_kernel<<<dim3(B_TOK * CDIM / 4 / 256), dim3(256), 0, stream>>>(
      ybuf, slot2row, eidx, wgt, b2, out);
}

// Round 21
// 262.842 us; speedup vs baseline: 1.0709x; 1.0709x over previous
//
#include <hip/hip_runtime.h>
#include <hip/hip_bf16.h>
#include <math.h>

#define B_TOK 8192
#define DDIM 1024
#define NEXP 8
#define HDIM 2048
#define CDIM 512
#define LN_EPS 1e-5f
#define MAXT256 72
#define MAXROWS (MAXT256 * 256)

typedef __attribute__((ext_vector_type(4))) float f32x4;
typedef __attribute__((ext_vector_type(8))) short bf16x8;

__device__ __forceinline__ unsigned short f2bf(float f) {
  __hip_bfloat16 h = __float2bfloat16(f);
  return *reinterpret_cast<unsigned short*>(&h);
}
__device__ __forceinline__ float bf2f(unsigned short u) {
  unsigned int x = ((unsigned int)u) << 16;
  return *reinterpret_cast<float*>(&x);
}

// gelu tanh-form via sigmoid identity: ~9 VALU ops, max dev vs exact ~3e-4
__device__ __forceinline__ float gelu_f(float v) {
  const float t = __builtin_fmaf(0.044715f * v, v, 1.0f);
  const float u = -1.5957691216f * v * t;
  return v * __builtin_amdgcn_rcpf(1.0f + __expf(u));
}

__device__ __forceinline__ void gload_lds16(const unsigned short* g, unsigned short* l) {
  __builtin_amdgcn_global_load_lds(
      (const __attribute__((address_space(1))) unsigned int*)g,
      (__attribute__((address_space(3))) unsigned int*)l, 16, 0, 0);
}

// ---------------- Router + LayerNorm (1 wave per token) ----------------
__global__ __launch_bounds__(256) void router_ln_kernel(
    const float* __restrict__ x, const float* __restrict__ Wr,
    const float* __restrict__ br, int* __restrict__ eidx,
    float* __restrict__ wgt, unsigned short* __restrict__ xn) {
  const int wid = threadIdx.x >> 6;
  const int lane = threadIdx.x & 63;
  const int tok = blockIdx.x * 4 + wid;

  const float4* xr = reinterpret_cast<const float4*>(x + (size_t)tok * DDIM);
  float4 xv[4];
  float sum = 0.f, sumsq = 0.f;
  float dot[NEXP];
#pragma unroll
  for (int e = 0; e < NEXP; ++e) dot[e] = 0.f;

#pragma unroll
  for (int i = 0; i < 4; ++i) {
    const int f = i * 64 + lane;
    float4 v = xr[f];
    xv[i] = v;
    sum += v.x + v.y + v.z + v.w;
    sumsq += v.x * v.x + v.y * v.y + v.z * v.z + v.w * v.w;
#pragma unroll
    for (int e = 0; e < NEXP; ++e) {
      float4 w = reinterpret_cast<const float4*>(Wr + e * DDIM)[f];
      dot[e] += v.x * w.x + v.y * w.y + v.z * w.z + v.w * w.w;
    }
  }
#pragma unroll
  for (int off = 32; off > 0; off >>= 1) {
    sum += __shfl_xor(sum, off);
    sumsq += __shfl_xor(sumsq, off);
#pragma unroll
    for (int e = 0; e < NEXP; ++e) dot[e] += __shfl_xor(dot[e], off);
  }
  const float mu = sum * (1.f / DDIM);
  const float var = sumsq * (1.f / DDIM) - mu * mu;
  const float rs = rsqrtf(var + LN_EPS);

  float lg[NEXP];
#pragma unroll
  for (int e = 0; e < NEXP; ++e) lg[e] = dot[e] + br[e];

  int i1 = 0; float v1 = lg[0];
#pragma unroll
  for (int e = 1; e < NEXP; ++e) { if (lg[e] > v1) { v1 = lg[e]; i1 = e; } }
  int i2 = -1; float v2 = -3.4e38f;
#pragma unroll
  for (int e = 0; e < NEXP; ++e) { if (e != i1 && lg[e] > v2) { v2 = lg[e]; i2 = e; } }

  const float e2 = __expf(v2 - v1);
  const float inv = 1.f / (1.f + e2);
  if (lane == 0) {
    eidx[tok * 2] = i1; eidx[tok * 2 + 1] = i2;
    wgt[tok * 2] = inv; wgt[tok * 2 + 1] = e2 * inv;
  }

  unsigned short* xnr = xn + (size_t)tok * DDIM;
#pragma unroll
  for (int i = 0; i < 4; ++i) {
    const int f = i * 64 + lane;
    float4 v = xv[i];
    ushort4 o;
    o.x = f2bf((v.x - mu) * rs);
    o.y = f2bf((v.y - mu) * rs);
    o.z = f2bf((v.z - mu) * rs);
    o.w = f2bf((v.w - mu) * rs);
    reinterpret_cast<ushort4*>(xnr)[f] = o;
  }
}

// ---------------- Counting sort into 256-row expert tiles ----------------
__global__ __launch_bounds__(256) void sort_kernel(
    const int* __restrict__ eidx,   // [B*2]
    int* __restrict__ tokRow,       // [MAXROWS]
    int* __restrict__ slot2row,     // [B*2]
    int* __restrict__ tileExp,      // [MAXT256]
    int* __restrict__ nTilesOut) {
  __shared__ int cnt[NEXP], segBase[NEXP], cur[NEXP];
  const int tid = threadIdx.x;
  if (tid < NEXP) { cnt[tid] = 0; cur[tid] = 0; }
  __syncthreads();
  for (int t = tid; t < B_TOK * 2; t += 256)
    atomicAdd(&cnt[eidx[t]], 1);
  __syncthreads();
  if (tid == 0) {
    int c = 0;
    for (int e = 0; e < NEXP; ++e) {
      segBase[e] = c;
      const int nt = (cnt[e] + 255) >> 8;
      for (int t = 0; t < nt; ++t) tileExp[(c >> 8) + t] = e;
      for (int p = c + cnt[e]; p < c + nt * 256; ++p) tokRow[p] = 0;
      c += nt * 256;
    }
    *nTilesOut = c >> 8;
  }
  __syncthreads();
  for (int t = tid; t < B_TOK * 2; t += 256) {
    const int e = eidx[t];
    const int pos = segBase[e] + atomicAdd(&cur[e], 1);
    tokRow[pos] = t >> 1;
    slot2row[t] = pos;
  }
}

// ---------------- Fold gamma/beta into W1: W1g bf16, c1 = beta@W1.T + b1 ----------------
__global__ __launch_bounds__(256) void prep_w1_kernel(
    const float* __restrict__ W1, const float* __restrict__ gamma,
    const float* __restrict__ beta, const float* __restrict__ b1,
    unsigned short* __restrict__ W1g, float* __restrict__ c1) {
  const int eh = blockIdx.x;
  const int e = eh >> 11;
  const int tid = threadIdx.x;

  float4 w = reinterpret_cast<const float4*>(W1 + (size_t)eh * DDIM)[tid];
  float4 g = reinterpret_cast<const float4*>(gamma + (size_t)e * DDIM)[tid];
  float4 bt = reinterpret_cast<const float4*>(beta + (size_t)e * DDIM)[tid];

  ushort4 o;
  o.x = f2bf(w.x * g.x); o.y = f2bf(w.y * g.y);
  o.z = f2bf(w.z * g.z); o.w = f2bf(w.w * g.w);
  reinterpret_cast<ushort4*>(W1g + (size_t)eh * DDIM)[tid] = o;

  float p = w.x * bt.x + w.y * bt.y + w.z * bt.z + w.w * bt.w;
#pragma unroll
  for (int off = 32; off > 0; off >>= 1) p += __shfl_xor(p, off);
  __shared__ float red[4];
  const int lane = tid & 63, wv = tid >> 6;
  if (lane == 0) red[wv] = p;
  __syncthreads();
  if (tid == 0) c1[eh] = b1[eh] + red[0] + red[1] + red[2] + red[3];
}

// ---------------- W2 f32 -> bf16 ----------------
__global__ __launch_bounds__(256) void prep_w2_kernel(
    const float* __restrict__ W2, unsigned short* __restrict__ W2b) {
  const int idx = blockIdx.x * 256 + threadIdx.x;
  float4 w = reinterpret_cast<const float4*>(W2)[idx];
  ushort4 o;
  o.x = f2bf(w.x); o.y = f2bf(w.y); o.z = f2bf(w.z); o.w = f2bf(w.w);
  reinterpret_cast<ushort4*>(W2b)[idx] = o;
}

// ---------------- GEMM1: 128x128, 2-deep dbuf LDS + counted vmcnt ----------------
#define BM 128
#define BN 128
#define BKK 64

__global__ __launch_bounds__(256) void gemm1_gelu_kernel(
    const unsigned short* __restrict__ A,    // xn [B,D] bf16
    const unsigned short* __restrict__ W1g,  // [E,H,D] bf16
    const float* __restrict__ c1,            // [E,H]
    const int* __restrict__ tokRow, const int* __restrict__ tileExp,
    const int* __restrict__ nTiles,
    unsigned short* __restrict__ Hout) {     // [MAXROWS,H] bf16
  // 2304 blocks: by=flat&15 (XCD = by%8 -> W-panels L2-pinned), bx window shared (A via L3)
  const int flat = blockIdx.x;
  const int by = flat & 15;
  const int bx = flat >> 4;            // [0,144)
  if ((bx >> 1) >= *nTiles) return;
  const int e = tileExp[bx >> 1];

  __shared__ unsigned short lA[2][BM * BKK];   // 32 KiB x2
  __shared__ unsigned short lB[2][BN * BKK];   // 32 KiB x2  (total 64 KiB -> 2 blocks/CU)
  const int tid = threadIdx.x;
  const int lane = tid & 63;
  const int wid = tid >> 6;
  const int wr = wid >> 1, wc = wid & 1;
  const int l15 = lane & 15, l4 = lane >> 4;

  const unsigned short* Bbase = W1g + ((size_t)e * HDIM + (size_t)by * BN) * DDIM;

  const int r = tid >> 3;                              // 0..31
  const int swz = ((tid & 7) ^ (r & 7)) * 8;           // inverse-swizzled source offset
  const int dst = (tid & 7) * 8;                       // lane-linear LDS slot

  // hoisted global pointers (k advances via scalar offset)
  const unsigned short* aP[4];
  const unsigned short* bP[4];
#pragma unroll
  for (int i = 0; i < 4; ++i) {
    aP[i] = A + (size_t)tokRow[bx * BM + i * 32 + r] * DDIM + swz;
    bP[i] = Bbase + (size_t)(i * 32 + r) * DDIM + swz;
  }

  f32x4 acc[4][4];   // [nn][mm]
#pragma unroll
  for (int n = 0; n < 4; ++n)
#pragma unroll
    for (int m = 0; m < 4; ++m)
#pragma unroll
      for (int j = 0; j < 4; ++j) acc[n][m][j] = 0.f;

  auto stage = [&](int b, int k0) {
#pragma unroll
    for (int i = 0; i < 4; ++i)
      gload_lds16(aP[i] + k0, &lA[b][(i * 32 + r) * BKK + dst]);
#pragma unroll
    for (int i = 0; i < 4; ++i)
      gload_lds16(bP[i] + k0, &lB[b][(i * 32 + r) * BKK + dst]);
  };

  // prologue: 2 tiles in flight (16 loads/thread outstanding)
  stage(0, 0);
  stage(1, BKK);

#pragma unroll 1
  for (int it = 0; it < 16; ++it) {
    if (it < 15) asm volatile("s_waitcnt vmcnt(8)" ::: "memory");
    else         asm volatile("s_waitcnt vmcnt(0)" ::: "memory");
    __builtin_amdgcn_sched_barrier(0);
    asm volatile("s_barrier" ::: "memory");
    const unsigned short* la = lA[it & 1];
    const unsigned short* lb = lB[it & 1];
#pragma unroll
    for (int kk = 0; kk < 2; ++kk) {
      bf16x8 xf[4], wf[4];
      const int slot = (((kk * 4 + l4) ^ (l15 & 7)) * 8);
#pragma unroll
      for (int m = 0; m < 4; ++m)
        xf[m] = *reinterpret_cast<const bf16x8*>(
            &la[(wr * 64 + m * 16 + l15) * BKK + slot]);
#pragma unroll
      for (int n = 0; n < 4; ++n)
        wf[n] = *reinterpret_cast<const bf16x8*>(
            &lb[(wc * 64 + n * 16 + l15) * BKK + slot]);
      // swapped operands: D(ar=W n-idx, br=token)
#pragma unroll
      for (int n = 0; n < 4; ++n)
#pragma unroll
        for (int m = 0; m < 4; ++m)
          acc[n][m] = __builtin_amdgcn_mfma_f32_16x16x32_bf16(wf[n], xf[m], acc[n][m], 0, 0, 0);
    }
    asm volatile("s_barrier" ::: "memory");
    if (it < 14) stage(it & 1, (it + 2) * BKK);
  }

  const int row0 = bx * BM + wr * 64;   // token base
  const int col0 = by * BN + wc * 64;   // h base
  const float* biasp = c1 + e * HDIM;
#pragma unroll
  for (int n = 0; n < 4; ++n) {
    const int hb = col0 + n * 16 + l4 * 4;
    const float4 b4 = *reinterpret_cast<const float4*>(biasp + hb);
#pragma unroll
    for (int m = 0; m < 4; ++m) {
      const int tokr = row0 + m * 16 + l15;
      ushort4 o;
      o.x = f2bf(gelu_f(acc[n][m][0] + b4.x));
      o.y = f2bf(gelu_f(acc[n][m][1] + b4.y));
      o.z = f2bf(gelu_f(acc[n][m][2] + b4.z));
      o.w = f2bf(gelu_f(acc[n][m][3] + b4.w));
      *reinterpret_cast<ushort4*>(&Hout[(size_t)tokr * HDIM + hb]) = o;
    }
  }
}

// ---------------- GEMM2: 128x128, swizzled LDS, swapped vec epilogue (R14/R19 form) ----------------
__global__ __launch_bounds__(256) void gemm2_kernel(
    const unsigned short* __restrict__ Hbuf,  // [MAXROWS,H] bf16
    const unsigned short* __restrict__ W2b,   // [E,C,H] bf16
    const int* __restrict__ tileExp, const int* __restrict__ nTiles,
    unsigned short* __restrict__ Y) {         // [MAXROWS,C] bf16
  // 576 blocks: XCD p=flat&7 owns by=p>>1 and bx-half p&1.
  const int flat = blockIdx.x;
  const int p = flat & 7;
  const int q = flat >> 3;              // [0,72)
  const int by = p >> 1;                // [0,4)
  const int bx = (p & 1) * 72 + q;      // [0,144)
  if ((bx >> 1) >= *nTiles) return;
  const int e = tileExp[bx >> 1];

  __shared__ unsigned short lA[BM * BKK];
  __shared__ unsigned short lB[BN * BKK];
  const int tid = threadIdx.x;
  const int lane = tid & 63;
  const int wid = tid >> 6;
  const int wr = wid >> 1, wc = wid & 1;
  const int l15 = lane & 15, l4 = lane >> 4;

  const unsigned short* Abase = Hbuf + (size_t)bx * BM * HDIM;
  const unsigned short* Bbase = W2b + ((size_t)e * CDIM + (size_t)by * BN) * HDIM;

  f32x4 acc[4][4];   // [nn][mm]
#pragma unroll
  for (int n = 0; n < 4; ++n)
#pragma unroll
    for (int m = 0; m < 4; ++m)
#pragma unroll
      for (int j = 0; j < 4; ++j) acc[n][m][j] = 0.f;

  const int r = tid >> 3;
  const int swz = ((tid & 7) ^ (r & 7)) * 8;
  const int dst = (tid & 7) * 8;

  for (int k0 = 0; k0 < HDIM; k0 += BKK) {
#pragma unroll
    for (int i = 0; i < 4; ++i)
      gload_lds16(Abase + (size_t)(i * 32 + r) * HDIM + k0 + swz,
                  &lA[(i * 32 + r) * BKK + dst]);
#pragma unroll
    for (int i = 0; i < 4; ++i)
      gload_lds16(Bbase + (size_t)(i * 32 + r) * HDIM + k0 + swz,
                  &lB[(i * 32 + r) * BKK + dst]);
    __syncthreads();
#pragma unroll
    for (int kk = 0; kk < 2; ++kk) {
      bf16x8 xf[4], wf[4];
      const int slot = (((kk * 4 + l4) ^ (l15 & 7)) * 8);
#pragma unroll
      for (int m = 0; m < 4; ++m)
        xf[m] = *reinterpret_cast<const bf16x8*>(
            &lA[(wr * 64 + m * 16 + l15) * BKK + slot]);
#pragma unroll
      for (int n = 0; n < 4; ++n)
        wf[n] = *reinterpret_cast<const bf16x8*>(
            &lB[(wc * 64 + n * 16 + l15) * BKK + slot]);
#pragma unroll
      for (int n = 0; n < 4; ++n)
#pragma unroll
        for (int m = 0; m < 4; ++m)
          acc[n][m] = __builtin_amdgcn_mfma_f32_16x16x32_bf16(wf[n], xf[m], acc[n][m], 0, 0, 0);
    }
    __syncthreads();
  }

  const int row0 = bx * BM + wr * 64;   // token base
  const int col0 = by * BN + wc * 64;   // C base
#pragma unroll
  for (int n = 0; n < 4; ++n) {
    const int cb = col0 + n * 16 + l4 * 4;
#pragma unroll
    for (int m = 0; m < 4; ++m) {
      const int tokr = row0 + m * 16 + l15;
      ushort4 o;
      o.x = f2bf(acc[n][m][0]);
      o.y = f2bf(acc[n][m][1]);
      o.z = f2bf(acc[n][m][2]);
      o.w = f2bf(acc[n][m][3]);
      *reinterpret_cast<ushort4*>(&Y[(size_t)tokr * CDIM + cb]) = o;
    }
  }
}

// ---------------- Combine: out[b,c] = sum_j w_j * (y[r_j,c] + b2[e_j,c]) ----------------
__global__ __launch_bounds__(256) void combine_kernel(
    const unsigned short* __restrict__ Y, const int* __restrict__ slot2row,
    const int* __restrict__ eidx, const float* __restrict__ wgt,
    const float* __restrict__ b2, float* __restrict__ out) {
  const int idx = blockIdx.x * 256 + threadIdx.x;
  const int b = idx >> 7;
  const int c4 = (idx & 127) * 4;
  const int r0 = slot2row[b * 2], r1 = slot2row[b * 2 + 1];
  const int e0 = eidx[b * 2], e1 = eidx[b * 2 + 1];
  const float w0 = wgt[b * 2], w1 = wgt[b * 2 + 1];
  ushort4 y0 = *reinterpret_cast<const ushort4*>(Y + (size_t)r0 * CDIM + c4);
  ushort4 y1 = *reinterpret_cast<const ushort4*>(Y + (size_t)r1 * CDIM + c4);
  float4 bb0 = *reinterpret_cast<const float4*>(b2 + e0 * CDIM + c4);
  float4 bb1 = *reinterpret_cast<const float4*>(b2 + e1 * CDIM + c4);
  float4 o;
  o.x = w0 * (bf2f(y0.x) + bb0.x) + w1 * (bf2f(y1.x) + bb1.x);
  o.y = w0 * (bf2f(y0.y) + bb0.y) + w1 * (bf2f(y1.y) + bb1.y);
  o.z = w0 * (bf2f(y0.z) + bb0.z) + w1 * (bf2f(y1.z) + bb1.z);
  o.w = w0 * (bf2f(y0.w) + bb0.w) + w1 * (bf2f(y1.w) + bb1.w);
  *reinterpret_cast<float4*>(out + (size_t)b * CDIM + c4) = o;
}

extern "C" void kernel_launch(void* const* d_in, const int* in_sizes, int n_in,
                              void* d_out, int out_size, void* d_ws, size_t ws_size,
                              hipStream_t stream) {
  const float* x     = (const float*)d_in[0];
  const float* Wr    = (const float*)d_in[1];
  const float* br    = (const float*)d_in[2];
  const float* gamma = (const float*)d_in[3];
  const float* beta  = (const float*)d_in[4];
  const float* W1    = (const float*)d_in[5];
  const float* b1    = (const float*)d_in[6];
  const float* W2    = (const float*)d_in[7];
  const float* b2    = (const float*)d_in[8];
  float* out = (float*)d_out;

  char* ws = (char*)d_ws;
  unsigned short* xn   = (unsigned short*)(ws);
  unsigned short* W2b  = (unsigned short*)(ws);                          // alias of xn (dead after gemm1)
  unsigned short* hbuf = (unsigned short*)(ws + (size_t)16 * 1048576);
  unsigned short* W1g  = (unsigned short*)(ws + (size_t)88 * 1048576);
  unsigned short* ybuf = (unsigned short*)(ws + (size_t)88 * 1048576);   // alias of W1g
  char* misc           = ws + (size_t)120 * 1048576;
  float* c1      = (float*)(misc);
  int* eidx      = (int*)(misc + 65536);
  float* wgt     = (float*)(misc + 2 * 65536);
  int* slot2row  = (int*)(misc + 3 * 65536);
  int* tokRow    = (int*)(misc + 4 * 65536);
  int* tileExp   = (int*)(misc + 4 * 65536 + 131072);
  int* nTiles    = tileExp + MAXT256;

  router_ln_kernel<<<dim3(B_TOK / 4), dim3(256), 0, stream>>>(x, Wr, br, eidx, wgt, xn);
  sort_kernel<<<dim3(1), dim3(256), 0, stream>>>(eidx, tokRow, slot2row, tileExp, nTiles);
  prep_w1_kernel<<<dim3(NEXP * HDIM), dim3(256), 0, stream>>>(W1, gamma, beta, b1, W1g, c1);

  gemm1_gelu_kernel<<<dim3(2304), dim3(256), 0, stream>>>(
      xn, W1g, c1, tokRow, tileExp, nTiles, hbuf);

  prep_w2_kernel<<<dim3((NEXP * CDIM * HDIM / 4) / 256), dim3(256), 0, stream>>>(W2, W2b);

  gemm2_kernel<<<dim3(576), dim3(256), 0, stream>>>(
      hbuf, W2b, tileExp, nTiles, ybuf);
  combine_kernel<<<dim3(B_TOK * CDIM / 4 / 256), dim3(256), 0, stream>>>(
      ybuf, slot2row, eidx, wgt, b2, out);
}